// Round 1
// baseline (1436.437 us; speedup 1.0000x reference)
//
#include <hip/hip_runtime.h>
#include <math.h>

#define B 128
#define H 32
#define D 128
#define W_SZ 128
#define TOPK 96
#define E 4096
#define BE (B * E)           // 524288
#define RING (B * H * W_SZ * D)  // 67108864

// ---------------------------------------------------------------------------
// GEMM: Y[b,e] = sum_f X[b,f] * W[e,f] + bias[e]   (torch Linear: X @ W.T + b)
// Tile: M=128 (all batches), N=32 output cols per block, K staged in chunks
// of 32 through LDS (both operands transposed so compute reads are
// ds_read_b128). Per-thread register tile 4b x 4e -> 16 FMA per k.
// ---------------------------------------------------------------------------
struct GemmArgs {
    const float* X;
    const float* W0; const float* W1; const float* W2;
    const float* b0; const float* b1; const float* b2;
    float* Y0; float* Y1; float* Y2;
    int tiles_per_mat;   // E/32 = 128
};

__global__ __launch_bounds__(256) void gemm_kernel(GemmArgs a) {
    __shared__ float xt[32][132];  // xt[k][b]; stride 132 (16B aligned, pads banks)
    __shared__ float wt[32][36];   // wt[k][e_local]

    const int mat  = blockIdx.x / a.tiles_per_mat;
    const int tile = blockIdx.x % a.tiles_per_mat;
    const float* Wm = (mat == 0) ? a.W0 : (mat == 1) ? a.W1 : a.W2;
    const float* bm = (mat == 0) ? a.b0 : (mat == 1) ? a.b1 : a.b2;
    float*       Ym = (mat == 0) ? a.Y0 : (mat == 1) ? a.Y1 : a.Y2;

    const int e_base = tile * 32;
    const int t  = threadIdx.x;
    const int b0 = (t & 31) * 4;        // 4 consecutive batches
    const int eL = (t >> 5) * 4;        // 4 consecutive output cols (local)

    float acc[4][4];
    #pragma unroll
    for (int i = 0; i < 4; ++i)
        #pragma unroll
        for (int j = 0; j < 4; ++j) acc[i][j] = 0.0f;

    for (int kk = 0; kk < E; kk += 32) {
        // stage X^T chunk: 128 b x 32 k
        #pragma unroll
        for (int i = 0; i < 4; ++i) {
            int f = i * 256 + t;
            int b = f >> 3, c = f & 7;
            float4 xv = *(const float4*)(a.X + (size_t)b * E + kk + c * 4);
            xt[c * 4 + 0][b] = xv.x;
            xt[c * 4 + 1][b] = xv.y;
            xt[c * 4 + 2][b] = xv.z;
            xt[c * 4 + 3][b] = xv.w;
        }
        // stage W^T chunk: 32 e x 32 k
        {
            int e = t >> 3, c = t & 7;
            float4 wv = *(const float4*)(Wm + (size_t)(e_base + e) * E + kk + c * 4);
            wt[c * 4 + 0][e] = wv.x;
            wt[c * 4 + 1][e] = wv.y;
            wt[c * 4 + 2][e] = wv.z;
            wt[c * 4 + 3][e] = wv.w;
        }
        __syncthreads();

        #pragma unroll
        for (int k = 0; k < 32; ++k) {
            float4 xv = *(const float4*)&xt[k][b0];
            float4 wv = *(const float4*)&wt[k][eL];
            float xa[4] = {xv.x, xv.y, xv.z, xv.w};
            float wa[4] = {wv.x, wv.y, wv.z, wv.w};
            #pragma unroll
            for (int i = 0; i < 4; ++i)
                #pragma unroll
                for (int j = 0; j < 4; ++j)
                    acc[i][j] = fmaf(xa[i], wa[j], acc[i][j]);
        }
        __syncthreads();
    }

    float4 bv = *(const float4*)(bm + e_base + eL);
    float ba[4] = {bv.x, bv.y, bv.z, bv.w};
    #pragma unroll
    for (int i = 0; i < 4; ++i) {
        float4 yv;
        yv.x = acc[i][0] + ba[0];
        yv.y = acc[i][1] + ba[1];
        yv.z = acc[i][2] + ba[2];
        yv.w = acc[i][3] + ba[3];
        *(float4*)(Ym + (size_t)(b0 + i) * E + e_base + eL) = yv;
    }
}

// ---------------------------------------------------------------------------
// Attention: one block per (b,h). Copies ring->out with row idx replaced,
// computes dist^2 scores, top-96 set selection (rank via O(W^2) compare,
// tie-break on rolled position to match jax.lax.top_k), softmax, weighted V.
// Roll itself is skipped: the (score, V-row) pairing is rotation-invariant.
// ---------------------------------------------------------------------------
__global__ __launch_bounds__(256) void attn_kernel(
    const float* __restrict__ qbuf, const float* __restrict__ kbuf,
    const float* __restrict__ vbuf, const float* __restrict__ log_sigma,
    const float* __restrict__ K_ring, const float* __restrict__ V_ring,
    float* __restrict__ K_new, float* __restrict__ V_new,
    float* __restrict__ cons, const int* __restrict__ cur_pos_p) {

    __shared__ float sq[128], skc[128], svc[128], sd[128], sp[128];
    __shared__ float scons[4][128];

    const int bh = blockIdx.x;
    const int b = bh / H, h = bh % H;
    const int t = threadIdx.x;
    const int wave = t >> 6, lane = t & 63;
    const size_t base = (size_t)bh * (W_SZ * D);
    const size_t qoff = (size_t)b * E + h * D;

    const int cur_pos = *cur_pos_p;
    const int idx = cur_pos % W_SZ;
    const int start = (cur_pos + 1) % W_SZ;

    if (t < 128) {
        sq[t]  = qbuf[qoff + t];
        skc[t] = kbuf[qoff + t];
        svc[t] = vbuf[qoff + t];
    }
    __syncthreads();

    // ---- K pass: copy + dist^2 ----
    for (int w = wave; w < W_SZ; w += 4) {
        float2 kv;
        if (w == idx) {
            kv.x = skc[2 * lane]; kv.y = skc[2 * lane + 1];
        } else {
            kv = *(const float2*)(K_ring + base + (size_t)w * D + 2 * lane);
        }
        *(float2*)(K_new + base + (size_t)w * D + 2 * lane) = kv;
        float d0 = sq[2 * lane] - kv.x;
        float d1 = sq[2 * lane + 1] - kv.y;
        float ss = d0 * d0 + d1 * d1;
        #pragma unroll
        for (int off = 32; off; off >>= 1) ss += __shfl_down(ss, off);
        if (lane == 0) sd[w] = ss;
    }
    __syncthreads();

    // ---- scores ----
    const float inv2s = 0.5f * expf(-2.0f * log_sigma[h]);  // 1/(2*sigma^2)
    if (t < 128) sd[t] = -sd[t] * inv2s;
    __syncthreads();

    // ---- top-96 set + exp ----
    float my_e = 0.0f;
    if (t < 128) {
        const float my_s = sd[t];
        const int my_p = (t - start) & (W_SZ - 1);  // rolled position
        int rank = 0;
        float mx = -1e30f;
        for (int w2 = 0; w2 < W_SZ; ++w2) {
            float s2 = sd[w2];
            mx = fmaxf(mx, s2);
            int p2 = (w2 - start) & (W_SZ - 1);
            rank += (s2 > my_s) || (s2 == my_s && p2 < my_p);
        }
        if (rank < TOPK) my_e = expf(my_s - mx);
    }
    __syncthreads();
    if (t < 128) sp[t] = my_e;
    __syncthreads();

    float denom = 0.0f;
    for (int w2 = 0; w2 < W_SZ; ++w2) denom += sp[w2];
    const float invd = 1.0f / denom;

    // ---- V pass: copy + weighted sum ----
    float ax = 0.0f, ay = 0.0f;
    for (int w = wave; w < W_SZ; w += 4) {
        float2 vv;
        if (w == idx) {
            vv.x = svc[2 * lane]; vv.y = svc[2 * lane + 1];
        } else {
            vv = *(const float2*)(V_ring + base + (size_t)w * D + 2 * lane);
        }
        *(float2*)(V_new + base + (size_t)w * D + 2 * lane) = vv;
        float pw = sp[w] * invd;
        ax = fmaf(pw, vv.x, ax);
        ay = fmaf(pw, vv.y, ay);
    }
    scons[wave][2 * lane]     = ax;
    scons[wave][2 * lane + 1] = ay;
    __syncthreads();
    if (t < 128) {
        cons[qoff + t] = scons[0][t] + scons[1][t] + scons[2][t] + scons[3][t];
    }
}

// ---------------------------------------------------------------------------
extern "C" void kernel_launch(void* const* d_in, const int* in_sizes, int n_in,
                              void* d_out, int out_size, void* d_ws, size_t ws_size,
                              hipStream_t stream) {
    (void)in_sizes; (void)n_in; (void)out_size; (void)ws_size;

    const float* x   = (const float*)d_in[0];
    const float* Wq  = (const float*)d_in[1];
    const float* bq  = (const float*)d_in[2];
    const float* Wk  = (const float*)d_in[3];
    const float* bk  = (const float*)d_in[4];
    const float* Wv  = (const float*)d_in[5];
    const float* bv  = (const float*)d_in[6];
    const float* Wo  = (const float*)d_in[7];
    const float* bo  = (const float*)d_in[8];
    const float* ls  = (const float*)d_in[9];
    const float* K_ring = (const float*)d_in[10];
    const float* V_ring = (const float*)d_in[11];
    const int*   cur_pos = (const int*)d_in[12];

    float* out   = (float*)d_out;
    float* K_new = out + BE;
    float* V_new = K_new + (size_t)RING;

    float* ws = (float*)d_ws;
    float* qb = ws;
    float* kb = ws + (size_t)BE;
    float* vb = ws + 2 * (size_t)BE;
    float* cb = ws + 3 * (size_t)BE;

    // QKV projections (single launch, 3 mats x 128 e-tiles = 384 blocks)
    GemmArgs ga;
    ga.X = x;
    ga.W0 = Wq; ga.W1 = Wk; ga.W2 = Wv;
    ga.b0 = bq; ga.b1 = bk; ga.b2 = bv;
    ga.Y0 = qb; ga.Y1 = kb; ga.Y2 = vb;
    ga.tiles_per_mat = E / 32;
    hipLaunchKernelGGL(gemm_kernel, dim3(3 * E / 32), dim3(256), 0, stream, ga);

    // Attention + ring copy (one block per (b,h))
    hipLaunchKernelGGL(attn_kernel, dim3(B * H), dim3(256), 0, stream,
                       qb, kb, vb, ls, K_ring, V_ring, K_new, V_new, cb, cur_pos);

    // Output projection
    GemmArgs go;
    go.X = cb;
    go.W0 = Wo; go.W1 = Wo; go.W2 = Wo;
    go.b0 = bo; go.b1 = bo; go.b2 = bo;
    go.Y0 = out; go.Y1 = out; go.Y2 = out;
    go.tiles_per_mat = E / 32;
    hipLaunchKernelGGL(gemm_kernel, dim3(E / 32), dim3(256), 0, stream, go);
}